// Round 3
// baseline (273.672 us; speedup 1.0000x reference)
//
#include <hip/hip_runtime.h>

#define C_COLS 16

typedef float nfloat4 __attribute__((ext_vector_type(4)));  // clang-native, OK for nontemporal builtins

// ---------------------------------------------------------------------------
// Kernel 1: reduce. Unrolled x4: each thread issues 4 independent float4
// loads per iteration (4 KB in flight per wave) before consuming any.
// Column group per thread is constant: all addresses are gid + k*stride with
// stride % 4 == 0, so group = (gid & 3) * 4.
// ---------------------------------------------------------------------------
__global__ __launch_bounds__(256) void k_reduce(const float4* __restrict__ x4,
                                                long long n4,
                                                float* __restrict__ partials) {
    const int tid = threadIdx.x;
    const long long gid = (long long)blockIdx.x * blockDim.x + tid;
    const long long stride = (long long)gridDim.x * blockDim.x;  // % 4 == 0

    float s0 = 0.f, s1 = 0.f, s2 = 0.f, s3 = 0.f;
    float c0 = 0.f, c1 = 0.f, c2 = 0.f, c3 = 0.f;

    long long i = gid;
    const long long step = stride * 4;
    for (; i + 3 * stride < n4; i += step) {
        float4 a = x4[i];
        float4 b = x4[i + stride];
        float4 c = x4[i + 2 * stride];
        float4 d = x4[i + 3 * stride];

        bool m;
        m = (a.x == a.x); s0 += m ? a.x : 0.f; c0 += m ? 1.f : 0.f;
        m = (a.y == a.y); s1 += m ? a.y : 0.f; c1 += m ? 1.f : 0.f;
        m = (a.z == a.z); s2 += m ? a.z : 0.f; c2 += m ? 1.f : 0.f;
        m = (a.w == a.w); s3 += m ? a.w : 0.f; c3 += m ? 1.f : 0.f;

        m = (b.x == b.x); s0 += m ? b.x : 0.f; c0 += m ? 1.f : 0.f;
        m = (b.y == b.y); s1 += m ? b.y : 0.f; c1 += m ? 1.f : 0.f;
        m = (b.z == b.z); s2 += m ? b.z : 0.f; c2 += m ? 1.f : 0.f;
        m = (b.w == b.w); s3 += m ? b.w : 0.f; c3 += m ? 1.f : 0.f;

        m = (c.x == c.x); s0 += m ? c.x : 0.f; c0 += m ? 1.f : 0.f;
        m = (c.y == c.y); s1 += m ? c.y : 0.f; c1 += m ? 1.f : 0.f;
        m = (c.z == c.z); s2 += m ? c.z : 0.f; c2 += m ? 1.f : 0.f;
        m = (c.w == c.w); s3 += m ? c.w : 0.f; c3 += m ? 1.f : 0.f;

        m = (d.x == d.x); s0 += m ? d.x : 0.f; c0 += m ? 1.f : 0.f;
        m = (d.y == d.y); s1 += m ? d.y : 0.f; c1 += m ? 1.f : 0.f;
        m = (d.z == d.z); s2 += m ? d.z : 0.f; c2 += m ? 1.f : 0.f;
        m = (d.w == d.w); s3 += m ? d.w : 0.f; c3 += m ? 1.f : 0.f;
    }
    for (; i < n4; i += stride) {
        float4 v = x4[i];
        bool m;
        m = (v.x == v.x); s0 += m ? v.x : 0.f; c0 += m ? 1.f : 0.f;
        m = (v.y == v.y); s1 += m ? v.y : 0.f; c1 += m ? 1.f : 0.f;
        m = (v.z == v.z); s2 += m ? v.z : 0.f; c2 += m ? 1.f : 0.f;
        m = (v.w == v.w); s3 += m ? v.w : 0.f; c3 += m ? 1.f : 0.f;
    }

    // Butterfly over lanes with identical (lane & 3): xor offsets 4..32.
    for (int off = 4; off < 64; off <<= 1) {
        s0 += __shfl_xor(s0, off, 64);
        s1 += __shfl_xor(s1, off, 64);
        s2 += __shfl_xor(s2, off, 64);
        s3 += __shfl_xor(s3, off, 64);
        c0 += __shfl_xor(c0, off, 64);
        c1 += __shfl_xor(c1, off, 64);
        c2 += __shfl_xor(c2, off, 64);
        c3 += __shfl_xor(c3, off, 64);
    }

    __shared__ float bsum[C_COLS];
    __shared__ float bcnt[C_COLS];
    if (tid < C_COLS) { bsum[tid] = 0.f; bcnt[tid] = 0.f; }
    __syncthreads();

    if ((tid & 63) < 4) {
        const int cb = (tid & 3) * 4;
        atomicAdd(&bsum[cb + 0], s0);
        atomicAdd(&bsum[cb + 1], s1);
        atomicAdd(&bsum[cb + 2], s2);
        atomicAdd(&bsum[cb + 3], s3);
        atomicAdd(&bcnt[cb + 0], c0);
        atomicAdd(&bcnt[cb + 1], c1);
        atomicAdd(&bcnt[cb + 2], c2);
        atomicAdd(&bcnt[cb + 3], c3);
    }
    __syncthreads();

    if (tid < C_COLS) {
        partials[(long long)blockIdx.x * 32 + tid] = bsum[tid];
        partials[(long long)blockIdx.x * 32 + 16 + tid] = bcnt[tid];
    }
}

// ---------------------------------------------------------------------------
// Kernel 2: single block, reduce nb partial rows -> mean[16] (+ scalar tail).
// ---------------------------------------------------------------------------
__global__ __launch_bounds__(256) void k_final(const float* __restrict__ partials,
                                               int nb,
                                               const float* __restrict__ x,
                                               long long n4, long long n,
                                               float* __restrict__ mean_out) {
    const int tid = threadIdx.x;
    const int c = tid & 15;
    const int r0 = tid >> 4;

    float s = 0.f, cnt = 0.f;
    for (int p = r0; p < nb; p += 16) {
        s   += partials[(long long)p * 32 + c];
        cnt += partials[(long long)p * 32 + 16 + c];
    }

    __shared__ float ssum[256];
    __shared__ float scnt[256];
    ssum[tid] = s;
    scnt[tid] = cnt;
    __syncthreads();

    if (tid < 16) {
        float S = 0.f, Cn = 0.f;
        for (int r = 0; r < 16; ++r) {
            S  += ssum[r * 16 + tid];
            Cn += scnt[r * 16 + tid];
        }
        for (long long j = n4 * 4; j < n; ++j) {
            if ((int)(j % 16) == tid) {
                float v = x[j];
                if (v == v) { S += v; Cn += 1.f; }
            }
        }
        mean_out[tid] = S / fmaxf(Cn, 1.f);
    }
}

// ---------------------------------------------------------------------------
// Kernel 3: fill. Unrolled x4 (4 loads in flight), nontemporal stores so the
// output stream doesn't evict x from L3 (x was just cached by k_reduce).
// ---------------------------------------------------------------------------
__global__ __launch_bounds__(256) void k_fill(const float4* __restrict__ x4,
                                              float4* __restrict__ o4,
                                              long long n4, long long n,
                                              const float* __restrict__ mean) {
    const int tid = threadIdx.x;
    const long long gid = (long long)blockIdx.x * blockDim.x + tid;
    const long long stride = (long long)gridDim.x * blockDim.x;  // % 4 == 0

    const int cb = (int)(gid & 3) * 4;
    const float m0 = mean[cb + 0];
    const float m1 = mean[cb + 1];
    const float m2 = mean[cb + 2];
    const float m3 = mean[cb + 3];

    nfloat4* on4 = (nfloat4*)o4;

    long long i = gid;
    const long long step = stride * 4;
    for (; i + 3 * stride < n4; i += step) {
        float4 a = x4[i];
        float4 b = x4[i + stride];
        float4 c = x4[i + 2 * stride];
        float4 d = x4[i + 3 * stride];

        nfloat4 av = { (a.x == a.x) ? a.x : m0,
                       (a.y == a.y) ? a.y : m1,
                       (a.z == a.z) ? a.z : m2,
                       (a.w == a.w) ? a.w : m3 };
        nfloat4 bv = { (b.x == b.x) ? b.x : m0,
                       (b.y == b.y) ? b.y : m1,
                       (b.z == b.z) ? b.z : m2,
                       (b.w == b.w) ? b.w : m3 };
        nfloat4 cv = { (c.x == c.x) ? c.x : m0,
                       (c.y == c.y) ? c.y : m1,
                       (c.z == c.z) ? c.z : m2,
                       (c.w == c.w) ? c.w : m3 };
        nfloat4 dv = { (d.x == d.x) ? d.x : m0,
                       (d.y == d.y) ? d.y : m1,
                       (d.z == d.z) ? d.z : m2,
                       (d.w == d.w) ? d.w : m3 };

        __builtin_nontemporal_store(av, &on4[i]);
        __builtin_nontemporal_store(bv, &on4[i + stride]);
        __builtin_nontemporal_store(cv, &on4[i + 2 * stride]);
        __builtin_nontemporal_store(dv, &on4[i + 3 * stride]);
    }
    for (; i < n4; i += stride) {
        float4 v = x4[i];
        nfloat4 vv = { (v.x == v.x) ? v.x : m0,
                       (v.y == v.y) ? v.y : m1,
                       (v.z == v.z) ? v.z : m2,
                       (v.w == v.w) ? v.w : m3 };
        __builtin_nontemporal_store(vv, &on4[i]);
    }

    if (blockIdx.x == 0 && tid == 0) {  // scalar tail (unused for this shape)
        const float* x = (const float*)x4;
        float* o = (float*)o4;
        for (long long j = n4 * 4; j < n; ++j) {
            float v = x[j];
            o[j] = (v == v) ? v : mean[(int)(j % 16)];
        }
    }
}

extern "C" void kernel_launch(void* const* d_in, const int* in_sizes, int n_in,
                              void* d_out, int out_size, void* d_ws, size_t ws_size,
                              hipStream_t stream) {
    const float* x = (const float*)d_in[0];
    float* out = (float*)d_out;
    const long long n = (long long)in_sizes[0];
    const long long n4 = n / 4;

    int nb1 = 2048;
    {
        long long cap = ((long long)(ws_size / 4) - 16) / 32;
        if (cap < 1) cap = 1;
        if (nb1 > cap) nb1 = (int)cap;
    }
    float* partials = (float*)d_ws;
    float* mean = partials + (long long)nb1 * 32;

    k_reduce<<<nb1, 256, 0, stream>>>((const float4*)x, n4, partials);
    k_final<<<1, 256, 0, stream>>>(partials, nb1, x, n4, n, mean);

    const int nb3 = 2048;
    k_fill<<<nb3, 256, 0, stream>>>((const float4*)x, (float4*)out, n4, n, mean);
}